// Round 4
// baseline (987.817 us; speedup 1.0000x reference)
//
#include <hip/hip_runtime.h>
#include <stdint.h>

#define B_   8
#define D_   192      // Cin*3
#define N_   2048
#define KNb  11       // k+1

using u32 = uint32_t;
using u16 = unsigned short;
typedef _Float16 f16;
struct alignas(8) h4 { f16 x, y, z, w; };

// ---------------- K0: xxd[b][n] = sum_d xf[b,d,n]^2 (f64, exact-order) ----------------
__global__ __launch_bounds__(256) void xx_kernel(const float* __restrict__ xf, double* __restrict__ xxd){
  int g = blockIdx.x * 256 + threadIdx.x;            // 16384
  int b = g >> 11, n = g & 2047;
  const float* p = xf + (size_t)b * D_ * N_ + n;
  double s = 0.0;
  #pragma unroll 4
  for (int d = 0; d < D_; ++d){ double v = (double)p[(size_t)d * N_]; s = fma(v, v, s); }
  xxd[g] = s;
}

// ---------------- K1: fp32 kNN pass -> top-16 candidate window per point ----------------
// block 256; n-tile 32 rows x 128-col tiles; thread = 2 rows x 8 cols.
__global__ __launch_bounds__(256, 2) void knn_kernel(const float* __restrict__ xf,
                                                     const double* __restrict__ xxd,
                                                     u16* __restrict__ cand){
  __shared__ float lds[96*32 + 96*128 + 128];        // 61,952 B
  float* An  = lds;
  float* Am  = lds + 96*32;
  float* xxs = lds + 96*32 + 96*128;

  const int b  = blockIdx.y;
  const int n0 = blockIdx.x * 32;
  const int t  = threadIdx.x;
  const int rg = t >> 4;       // 0..15, 2 rows each
  const int cg = t & 15;       // 0..15, 8 cols each
  const size_t xb = (size_t)b * D_ * N_;

  float xxn[2];
  xxn[0] = (float)xxd[b*N_ + n0 + rg*2 + 0];
  xxn[1] = (float)xxd[b*N_ + n0 + rg*2 + 1];

  // ascending top-16 lists: [0] = current min
  float bv[2][16]; int bi[2][16];
  #pragma unroll
  for (int r = 0; r < 2; ++r)
    #pragma unroll
    for (int j = 0; j < 16; ++j){ bv[r][j] = -3.4e38f; bi[r][j] = 0; }

  for (int mt = 0; mt < 16; ++mt){
    const int m0 = mt * 128;
    float acc[2][8];
    #pragma unroll
    for (int r = 0; r < 2; ++r)
      #pragma unroll
      for (int j = 0; j < 8; ++j) acc[r][j] = 0.f;

    for (int h = 0; h < 2; ++h){
      __syncthreads();
      #pragma unroll
      for (int q = 0; q < 6; ++q){
        int p = t + 256*q;
        int d2 = p >> 4, i2 = (p & 15) * 2;
        float2 v = *(const float2*)(xf + xb + (size_t)(h*96 + d2)*N_ + n0 + i2);
        An[d2*32 + i2] = v.x; An[d2*32 + i2 + 1] = v.y;
      }
      #pragma unroll
      for (int q = 0; q < 24; ++q){
        int p = t + 256*q;
        int d2 = p >> 6, i2 = (p & 63) * 2;
        float2 v = *(const float2*)(xf + xb + (size_t)(h*96 + d2)*N_ + m0 + i2);
        Am[d2*128 + i2] = v.x; Am[d2*128 + i2 + 1] = v.y;
      }
      if (h == 0 && t < 128) xxs[t] = (float)xxd[b*N_ + m0 + t];
      __syncthreads();

      #pragma unroll 4
      for (int d2 = 0; d2 < 96; ++d2){
        const float2 rv = *(const float2*)&An[d2*32 + rg*2];
        const float4 c0 = *(const float4*)&Am[d2*128 + cg*8];
        const float4 c1 = *(const float4*)&Am[d2*128 + cg*8 + 4];
        acc[0][0] = fmaf(rv.x, c0.x, acc[0][0]);
        acc[0][1] = fmaf(rv.x, c0.y, acc[0][1]);
        acc[0][2] = fmaf(rv.x, c0.z, acc[0][2]);
        acc[0][3] = fmaf(rv.x, c0.w, acc[0][3]);
        acc[0][4] = fmaf(rv.x, c1.x, acc[0][4]);
        acc[0][5] = fmaf(rv.x, c1.y, acc[0][5]);
        acc[0][6] = fmaf(rv.x, c1.z, acc[0][6]);
        acc[0][7] = fmaf(rv.x, c1.w, acc[0][7]);
        acc[1][0] = fmaf(rv.y, c0.x, acc[1][0]);
        acc[1][1] = fmaf(rv.y, c0.y, acc[1][1]);
        acc[1][2] = fmaf(rv.y, c0.z, acc[1][2]);
        acc[1][3] = fmaf(rv.y, c0.w, acc[1][3]);
        acc[1][4] = fmaf(rv.y, c1.x, acc[1][4]);
        acc[1][5] = fmaf(rv.y, c1.y, acc[1][5]);
        acc[1][6] = fmaf(rv.y, c1.z, acc[1][6]);
        acc[1][7] = fmaf(rv.y, c1.w, acc[1][7]);
      }
    }

    #pragma unroll
    for (int r = 0; r < 2; ++r){
      #pragma unroll
      for (int j = 0; j < 8; ++j){
        float v = (2.f*acc[r][j] - xxn[r]) - xxs[cg*8 + j];
        int m = m0 + cg*8 + j;
        if (v > bv[r][0]){
          bv[r][0] = v; bi[r][0] = m;
          #pragma unroll
          for (int s = 0; s < 15; ++s){
            if (bv[r][s] > bv[r][s+1]){
              float tv = bv[r][s]; bv[r][s] = bv[r][s+1]; bv[r][s+1] = tv;
              int   ti = bi[r][s]; bi[r][s] = bi[r][s+1]; bi[r][s+1] = ti;
            }
          }
        }
      }
    }
  }

  // merge 16 per-thread lists per row -> block top-16 (values fp32, idx u16)
  __syncthreads();
  float* MV = lds;                               // 32*16*16 = 8192 floats (32 KB)
  u16*   MI = (u16*)(lds + 8192);                // 8192 u16 (16 KB)
  #pragma unroll
  for (int r = 0; r < 2; ++r){
    int row = rg*2 + r;
    #pragma unroll
    for (int j = 0; j < 16; ++j){
      MV[(row*16 + cg)*16 + j] = bv[r][j];
      MI[(row*16 + cg)*16 + j] = (u16)bi[r][j];
    }
  }
  __syncthreads();
  if (t < 32){
    const int row = t;
    int head[16];
    #pragma unroll
    for (int q = 0; q < 16; ++q) head[q] = 15;
    const size_t ob = ((size_t)b * N_ + n0 + row) * 16;
    for (int s = 0; s < 16; ++s){
      float bvv = -3.4e38f; int bm = 0; int bq = 0;
      #pragma unroll
      for (int q = 0; q < 16; ++q){
        int hh = head[q];
        bool valid = hh >= 0;
        float v = valid ? MV[(row*16 + q)*16 + hh] : -3.4e38f;
        int   m = valid ? (int)MI[(row*16 + q)*16 + hh] : 0;
        if (v > bvv){ bvv = v; bm = m; bq = q; }
      }
      cand[ob + s] = (u16)(bm & 2047);
      #pragma unroll
      for (int q = 0; q < 16; ++q) head[q] -= (q == bq) ? 1 : 0;
    }
  }
}

// ---------------- K1b: f64 exact refinement of the 16-candidate window -> top-11 ----------------
// one wave per point; lane = cand(16) x d-part(4)
__global__ __launch_bounds__(256) void refine_kernel(const float* __restrict__ xf,
                                                     const u16* __restrict__ cand,
                                                     const double* __restrict__ xxd,
                                                     int* __restrict__ idxout){
  __shared__ double dls[4][16];
  __shared__ int    mls[4][16];
  const int wv = threadIdx.x >> 6, ln = threadIdx.x & 63;
  const int g = blockIdx.x * 4 + wv;             // 0..16383
  const int b = g >> 11, n = g & 2047;
  const int c = ln >> 2, part = ln & 3;
  const int m = (int)cand[(size_t)g*16 + c] & 2047;
  const float* xb = xf + (size_t)b * D_ * N_;
  const float* pn = xb + (size_t)(part*48) * N_ + n;
  const float* pm = xb + (size_t)(part*48) * N_ + m;
  double s = 0.0;
  #pragma unroll 8
  for (int d = 0; d < 48; ++d)
    s = fma((double)pn[(size_t)d*N_], (double)pm[(size_t)d*N_], s);
  s += __shfl_down(s, 2, 64);
  s += __shfl_down(s, 1, 64);
  if (part == 0){
    dls[wv][c] = 2.0*s - xxd[b*N_ + n] - xxd[b*N_ + m];
    mls[wv][c] = m;
  }
  __syncthreads();
  if (ln == 0){
    double vv[16]; int mm[16];
    #pragma unroll
    for (int i = 0; i < 16; ++i){ vv[i] = dls[wv][i]; mm[i] = mls[wv][i]; }
    for (int s2 = 0; s2 < KNb; ++s2){
      int best = 0;
      #pragma unroll
      for (int i = 1; i < 16; ++i){
        bool better = (vv[i] > vv[best]) || ((vv[i] == vv[best]) && (mm[i] < mm[best]));
        if (better) best = i;
      }
      idxout[(size_t)g*KNb + s2] = mm[best];
      vv[best] = -1.0e308;
    }
  }
}

// ---------------- K2: P0/D0 = W_feat/W_dir @ xf per point (fp16 storage) ----------------
__global__ __launch_bounds__(256, 2) void project_kernel(const float* __restrict__ xf,
                                                         const float* __restrict__ Wf,
                                                         const float* __restrict__ Wd,
                                                         h4* __restrict__ P0h,
                                                         h4* __restrict__ D0h){
  __shared__ float A[D_ * 64];    // 48 KB, layout [d][m]
  const int b  = blockIdx.y;
  const int m0 = blockIdx.x * 64;
  const int t  = threadIdx.x;
  const int c  = t & 63;
  const int mg = t >> 6;
  const size_t xb = (size_t)b * D_ * N_;

  float wf[64], wd[64];
  #pragma unroll
  for (int q = 0; q < 32; ++q){
    float2 uf = *(const float2*)(Wf + c*64 + q*2);
    wf[q*2] = uf.x; wf[q*2+1] = uf.y;
    float2 ud = *(const float2*)(Wd + c*64 + q*2);
    wd[q*2] = ud.x; wd[q*2+1] = ud.y;
  }
  #pragma unroll
  for (int q = 0; q < 24; ++q){
    int p = t + 256*q;
    int d = p >> 5, i2 = (p & 31) * 2;
    float2 v = *(const float2*)(xf + xb + (size_t)d*N_ + m0 + i2);
    A[d*64 + i2] = v.x; A[d*64 + i2 + 1] = v.y;
  }
  __syncthreads();

  for (int mi = 0; mi < 16; ++mi){
    int m = mg*16 + mi;
    float p0=0,p1=0,p2=0,q0=0,q1=0,q2=0;
    #pragma unroll
    for (int ci = 0; ci < 64; ++ci){
      float f0 = A[(ci*3+0)*64 + m];
      float f1 = A[(ci*3+1)*64 + m];
      float f2 = A[(ci*3+2)*64 + m];
      p0 = fmaf(wf[ci], f0, p0); p1 = fmaf(wf[ci], f1, p1); p2 = fmaf(wf[ci], f2, p2);
      q0 = fmaf(wd[ci], f0, q0); q1 = fmaf(wd[ci], f1, q1); q2 = fmaf(wd[ci], f2, q2);
    }
    float nrm = sqrtf(p0*p0 + p1*p1 + p2*p2);
    float dsq = q0*q0 + q1*q1 + q2*q2;
    size_t base = ((size_t)b*N_ + m0 + m)*64 + c;
    h4 vp; vp.x = (f16)p0; vp.y = (f16)p1; vp.z = (f16)p2; vp.w = (f16)nrm;
    h4 vd; vd.x = (f16)q0; vd.y = (f16)q1; vd.z = (f16)q2; vd.w = (f16)dsq;
    P0h[base] = vp;
    D0h[base] = vd;
  }
}

// ---------------- K3a: neighbor occurrence counts ----------------
__global__ __launch_bounds__(256) void count_kernel(const int* __restrict__ idxin, int* __restrict__ cnt){
  int i = blockIdx.x*256 + threadIdx.x;
  if (i < B_*N_*KNb){
    int b = i / (N_*KNb);
    atomicAdd(&cnt[b*N_ + (idxin[i] & 2047)], 1);
  }
}

// ---------------- K3b: per-channel weighted sum / sumsq of norms ----------------
__global__ __launch_bounds__(256) void stats_kernel(const h4* __restrict__ P0h,
                                                    const int* __restrict__ cnt,
                                                    float* __restrict__ gs){
  const int b = blockIdx.x >> 3;
  const int chunk = blockIdx.x & 7;
  const int w = threadIdx.x >> 6, c = threadIdx.x & 63;
  float s = 0.f, s2 = 0.f;
  const int mbase = chunk*256 + w*64;
  for (int i = 0; i < 64; ++i){
    int m = mbase + i;
    float wt = (float)cnt[b*N_ + m];
    float nv = (float)P0h[((size_t)b*N_ + m)*64 + c].w;
    s  = fmaf(wt, nv, s);
    s2 = fmaf(wt*nv, nv, s2);
  }
  __shared__ float red[8][64];
  red[w][c] = s; red[4+w][c] = s2;
  __syncthreads();
  if (w == 0) atomicAdd(&gs[c],    red[0][c]+red[1][c]+red[2][c]+red[3][c]);
  if (w == 1) atomicAdd(&gs[64+c], red[4][c]+red[5][c]+red[6][c]+red[7][c]);
}

// ---------------- K4: gather + BN + nonlinearity + mean over K ----------------
__global__ __launch_bounds__(256) void out_kernel(const h4* __restrict__ P0h, const h4* __restrict__ D0h,
                                                  const int* __restrict__ idxin, const float* __restrict__ gs,
                                                  const float* __restrict__ gamma, const float* __restrict__ beta,
                                                  float* __restrict__ outp){
  const int b  = blockIdx.y;
  const int n0 = blockIdx.x * 32;
  const int w = threadIdx.x >> 6, c = threadIdx.x & 63;
  const float Ninv = 1.f / (float)(B_*N_*KNb);
  float mean = gs[c] * Ninv;
  float var  = gs[64+c] * Ninv - mean*mean;
  float istd = rsqrtf(var + 1e-5f);
  float sa = istd * gamma[c];
  float be = beta[c];
  for (int i = 0; i < 8; ++i){
    int n = n0 + w*8 + i;
    const int* ip = idxin + ((size_t)b*N_ + n)*KNb;
    float a0=0, a1=0, a2=0;
    #pragma unroll
    for (int k = 0; k < KNb; ++k){
      int m = ip[k] & 2047;              // clamp: never fault on bad idx
      size_t base = ((size_t)b*N_ + m)*64 + c;
      h4 P  = P0h[base];
      h4 Dv = D0h[base];
      float pw = (float)P.w;
      float nb = (pw - mean)*sa + be;
      float sc = nb / pw;
      float p0 = (float)P.x*sc, p1 = (float)P.y*sc, p2 = (float)P.z*sc;
      float d0 = (float)Dv.x, d1 = (float)Dv.y, d2 = (float)Dv.z;
      float dot = p0*d0 + p1*d1 + p2*d2;
      float f = (dot >= 0.f) ? 0.f : dot / ((float)Dv.w + 1e-6f);
      a0 += p0 - f*d0; a1 += p1 - f*d1; a2 += p2 - f*d2;
    }
    const float kinv = 1.f/11.f;
    size_t ob = (((size_t)b*64 + c)*3)*N_ + n;
    outp[ob]        = a0*kinv;
    outp[ob + N_]   = a1*kinv;
    outp[ob + 2*N_] = a2*kinv;
  }
}

extern "C" void kernel_launch(void* const* d_in, const int* in_sizes, int n_in,
                              void* d_out, int out_size, void* d_ws, size_t ws_size,
                              hipStream_t stream){
  const float* x     = (const float*)d_in[0];
  const float* Wf    = (const float*)d_in[1];
  const float* Wd    = (const float*)d_in[2];
  const float* gamma = (const float*)d_in[3];
  const float* beta  = (const float*)d_in[4];
  float* outp = (float*)d_out;

  // Workspace layout (total 17,564,160 B <= 17,629,696 proven safe in R1).
  // Aliases are safe by kernel ordering: cand/xxd consumed by refine BEFORE
  // project writes P0h/D0h over them.
  char* ws = (char*)d_ws;
  int*    idx  = (int*)   (ws);                  // 720,896 B
  h4*     P0h  = (h4*)    (ws + 720896);         // 8,388,608 B
  u16*    cand = (u16*)   (ws + 720896);         //   alias: 524,288 B
  h4*     D0h  = (h4*)    (ws + 9109504);        // 8,388,608 B
  double* xxd  = (double*)(ws + 9109504);        //   alias: 131,072 B
  int*    cnt  = (int*)   (ws + 17498112);       // 65,536 B
  float*  gs   = (float*) (ws + 17563648);       // 512 B

  hipMemsetAsync(cnt, 0, 65536 + 512, stream);   // zero cnt + gs
  xx_kernel     <<<64,           256, 0, stream>>>(x, xxd);
  knn_kernel    <<<dim3(64, 8),  256, 0, stream>>>(x, xxd, cand);
  refine_kernel <<<4096,         256, 0, stream>>>(x, cand, xxd, idx);
  project_kernel<<<dim3(32, 8),  256, 0, stream>>>(x, Wf, Wd, P0h, D0h);
  count_kernel  <<<704,          256, 0, stream>>>(idx, cnt);
  stats_kernel  <<<64,           256, 0, stream>>>(P0h, cnt, gs);
  out_kernel    <<<dim3(64, 8),  256, 0, stream>>>(P0h, D0h, idx, gs, gamma, beta, outp);
}

// Round 5
// 875.372 us; speedup vs baseline: 1.1285x; 1.1285x over previous
//
#include <hip/hip_runtime.h>
#include <stdint.h>

#define B_   8
#define D_   192      // Cin*3
#define N_   2048
#define KNb  11       // k+1

using u32 = uint32_t;
using u16 = unsigned short;
typedef _Float16 f16;
struct alignas(8) h4 { f16 x, y, z, w; };

typedef __attribute__((ext_vector_type(8)))  short short8;
typedef __attribute__((ext_vector_type(16))) float f32x16;

__device__ __forceinline__ float bf2f(u16 h){ union{u32 i; float f;} x; x.i = ((u32)h) << 16; return x.f; }
__device__ __forceinline__ u16 f2bf(float f){
  union{float f; u32 i;} x; x.f = f;
  u32 r = (x.i + 0x7fffu + ((x.i >> 16) & 1u)) >> 16;
  return (u16)r;
}

// ---------------- K0: bf16 hi/lo split transpose + f64 sum-of-squares ----------------
// Xs[b][m][k]: k in [0,192) = hi(x[b][k][m]), k in [192,384) = lo. Row = 768 B.
__global__ __launch_bounds__(256) void split_kernel(const float* __restrict__ x,
                                                    short* __restrict__ Xs,
                                                    double* __restrict__ xxd){
  __shared__ float A[D_ * 64];                       // 48 KB, [d][m]
  const int b = blockIdx.y, m0 = blockIdx.x * 64, t = threadIdx.x;
  const size_t xb = (size_t)b * D_ * N_;
  #pragma unroll
  for (int q = 0; q < 48; ++q){
    int p = t + 256*q;
    int d = p >> 6, i = p & 63;
    A[d*64 + i] = x[xb + (size_t)d*N_ + m0 + i];
  }
  __syncthreads();
  const int m = t & 63, seg = t >> 6;                // 4 segs of 48 d's per point
  short* orow = Xs + ((size_t)b*N_ + m0 + m) * 384;
  #pragma unroll
  for (int c8 = 0; c8 < 6; ++c8){
    u16 hp[8], lp[8];
    #pragma unroll
    for (int j = 0; j < 8; ++j){
      int d = seg*48 + c8*8 + j;
      float v = A[d*64 + m];
      u16 h = f2bf(v);
      float lo = v - bf2f(h);                        // exact in fp32
      hp[j] = h; lp[j] = f2bf(lo);
    }
    union { u16 s[8]; int4 v; } uh, ul;
    #pragma unroll
    for (int j = 0; j < 8; ++j){ uh.s[j] = hp[j]; ul.s[j] = lp[j]; }
    *(int4*)(orow + seg*48 + c8*8)       = uh.v;     // hi block
    *(int4*)(orow + 192 + seg*48 + c8*8) = ul.v;     // lo block
  }
  if (t < 64){
    double s = 0.0;
    #pragma unroll 4
    for (int d = 0; d < D_; ++d){ double v = (double)A[d*64 + t]; s = fma(v, v, s); }
    xxd[b*N_ + m0 + t] = s;
  }
}

// ---------------- K1: MFMA kNN (Gram over K=384 bf16 split) -> top-16 window ----------------
// 256 blocks (1/CU): block = (b, 64 n-rows) vs all 2048 m, in 8 m-tiles of 256.
// LDS: Xn 64x784B | Xm dbuf 2x256x80B | dist 64x257 f32 | xxs 256 f32  = 157,952 B
#define OFF_XM0 50176
#define OFF_XM1 70656
#define OFF_CT  91136
#define OFF_XXS 156928
__global__ __launch_bounds__(256, 1) void knn_kernel(const short* __restrict__ Xs,
                                                     const double* __restrict__ xxd,
                                                     u16* __restrict__ cand){
  __shared__ __align__(16) char smem[157952];
  char* XN = smem;
  float* CT  = (float*)(smem + OFF_CT);
  float* XXS = (float*)(smem + OFF_XXS);

  const int b = blockIdx.y, n0 = blockIdx.x * 64;
  const int t = threadIdx.x, lane = t & 63, w = t >> 6;
  const int l31 = lane & 31, lh = lane >> 5;

  // stage Xn rows (64 x 768 B -> padded 784 B rows)
  {
    const char* src = (const char*)(Xs + ((size_t)b*N_ + n0) * 384);
    int r = t >> 2, q = t & 3;
    const int4* gsv = (const int4*)(src + r*768 + q*192);
    int4* dsv = (int4*)(XN + r*784 + q*192);
    #pragma unroll
    for (int j = 0; j < 12; ++j) dsv[j] = gsv[j];
  }
  const float xxn = (float)xxd[b*N_ + n0 + lane];

  float bv[16]; int bi[16];
  #pragma unroll
  for (int j = 0; j < 16; ++j){ bv[j] = -3.4e38f; bi[j] = 0; }

  const char* xsrow = (const char*)(Xs + (size_t)b*N_*384);

  for (int mt = 0; mt < 8; ++mt){
    const int m0 = mt * 256;
    XXS[t] = (float)xxd[b*N_ + m0 + t];
    {   // stage K-chunk 0
      const int4* g = (const int4*)(xsrow + (size_t)(m0 + t)*768);
      int4* d = (int4*)(smem + OFF_XM0 + t*80);
      #pragma unroll
      for (int j = 0; j < 4; ++j) d[j] = g[j];
    }
    __syncthreads();

    f32x16 acc00 = (f32x16)0.0f, acc01 = (f32x16)0.0f;
    f32x16 acc10 = (f32x16)0.0f, acc11 = (f32x16)0.0f;

    for (int kc = 0; kc < 12; ++kc){
      const char* cur = smem + ((kc & 1) ? OFF_XM1 : OFF_XM0);
      int4 p0, p1, p2, p3;
      const bool pf = kc < 11;
      if (pf){
        const int4* g = (const int4*)(xsrow + (size_t)(m0 + t)*768 + (kc+1)*64);
        p0 = g[0]; p1 = g[1]; p2 = g[2]; p3 = g[3];
      }
      #pragma unroll
      for (int ks = 0; ks < 2; ++ks){
        const int ka = kc*64 + ks*32 + lh*16;          // byte offset in Xn row
        const int kb = ks*32 + lh*16;                  // byte offset in Xm row
        short8 a0 = *(const short8*)(XN + l31*784 + ka);
        short8 a1 = *(const short8*)(XN + (l31 + 32)*784 + ka);
        short8 b0 = *(const short8*)(cur + (w*64 + l31)*80 + kb);
        short8 b1 = *(const short8*)(cur + (w*64 + 32 + l31)*80 + kb);
        acc00 = __builtin_amdgcn_mfma_f32_32x32x16_bf16(a0, b0, acc00, 0, 0, 0);
        acc01 = __builtin_amdgcn_mfma_f32_32x32x16_bf16(a0, b1, acc01, 0, 0, 0);
        acc10 = __builtin_amdgcn_mfma_f32_32x32x16_bf16(a1, b0, acc10, 0, 0, 0);
        acc11 = __builtin_amdgcn_mfma_f32_32x32x16_bf16(a1, b1, acc11, 0, 0, 0);
      }
      if (pf){
        int4* d = (int4*)(smem + (((kc+1) & 1) ? OFF_XM1 : OFF_XM0) + t*80);
        d[0] = p0; d[1] = p1; d[2] = p2; d[3] = p3;
      }
      __syncthreads();
    }

    // scatter accs -> CT[n][m] (stride 257 floats: conflict-free)
    {
      const int colb = w*64 + l31;
      const int rowb = 4*lh;
      #pragma unroll
      for (int g = 0; g < 4; ++g)
        #pragma unroll
        for (int j = 0; j < 4; ++j){
          CT[(rowb + 8*g + j)*257 + colb]           = acc00[g*4 + j];
          CT[(rowb + 8*g + j)*257 + colb + 32]      = acc01[g*4 + j];
          CT[(rowb + 32 + 8*g + j)*257 + colb]      = acc10[g*4 + j];
          CT[(rowb + 32 + 8*g + j)*257 + colb + 32] = acc11[g*4 + j];
        }
    }
    __syncthreads();

    // per-thread top-16 over this thread's m-quarter
    {
      const float* ct = CT + lane*257 + w*64;
      const float* xs = XXS + w*64;
      for (int i = 0; i < 64; ++i){
        float v = 2.f*ct[i] - xs[i] - xxn;
        int m = m0 + w*64 + i;
        if (v > bv[0]){
          bv[0] = v; bi[0] = m;
          #pragma unroll
          for (int s = 0; s < 15; ++s){
            if (bv[s] > bv[s+1]){
              float tv = bv[s]; bv[s] = bv[s+1]; bv[s+1] = tv;
              int   ti = bi[s]; bi[s] = bi[s+1]; bi[s+1] = ti;
            }
          }
        }
      }
    }
    __syncthreads();
  }

  // merge 4 per-thread lists per row -> top-16 window
  float* MV = CT;                  // [64 rows][4 lists][16]
  u16*   MI = (u16*)(CT + 4096);
  #pragma unroll
  for (int j = 0; j < 16; ++j){
    MV[(lane*4 + w)*16 + j] = bv[j];
    MI[(lane*4 + w)*16 + j] = (u16)bi[j];
  }
  __syncthreads();
  if (t < 64){
    int head[4] = {15, 15, 15, 15};
    const size_t ob = ((size_t)b*N_ + n0 + t) * 16;
    for (int s = 0; s < 16; ++s){
      float bvv = -3.4e38f; int bm = 0x7fffffff, bq = 0;
      #pragma unroll
      for (int q = 0; q < 4; ++q){
        int hh = head[q];
        if (hh >= 0){
          float v = MV[(t*4 + q)*16 + hh];
          int   m = (int)MI[(t*4 + q)*16 + hh];
          if ((v > bvv) || ((v == bvv) && (m < bm))){ bvv = v; bm = m; bq = q; }
        }
      }
      cand[ob + s] = (u16)(bm & 2047);
      head[bq]--;
    }
  }
}

// ---------------- K1b: f64 exact refinement of the 16-candidate window -> top-11 ----------------
__global__ __launch_bounds__(256) void refine_kernel(const float* __restrict__ xf,
                                                     const u16* __restrict__ cand,
                                                     const double* __restrict__ xxd,
                                                     int* __restrict__ idxout){
  __shared__ double dls[4][16];
  __shared__ int    mls[4][16];
  const int wv = threadIdx.x >> 6, ln = threadIdx.x & 63;
  const int g = blockIdx.x * 4 + wv;
  const int b = g >> 11, n = g & 2047;
  const int c = ln >> 2, part = ln & 3;
  const int m = (int)cand[(size_t)g*16 + c] & 2047;
  const float* xb = xf + (size_t)b * D_ * N_;
  const float* pn = xb + (size_t)(part*48) * N_ + n;
  const float* pm = xb + (size_t)(part*48) * N_ + m;
  double s = 0.0;
  #pragma unroll 8
  for (int d = 0; d < 48; ++d)
    s = fma((double)pn[(size_t)d*N_], (double)pm[(size_t)d*N_], s);
  s += __shfl_down(s, 2, 64);
  s += __shfl_down(s, 1, 64);
  if (part == 0){
    dls[wv][c] = 2.0*s - xxd[b*N_ + n] - xxd[b*N_ + m];
    mls[wv][c] = m;
  }
  __syncthreads();
  if (ln == 0){
    double vv[16]; int mm[16];
    #pragma unroll
    for (int i = 0; i < 16; ++i){ vv[i] = dls[wv][i]; mm[i] = mls[wv][i]; }
    for (int s2 = 0; s2 < KNb; ++s2){
      int best = 0;
      #pragma unroll
      for (int i = 1; i < 16; ++i){
        bool better = (vv[i] > vv[best]) || ((vv[i] == vv[best]) && (mm[i] < mm[best]));
        if (better) best = i;
      }
      idxout[(size_t)g*KNb + s2] = mm[best];
      vv[best] = -1.0e308;
    }
  }
}

// ---------------- K2: P0/D0 = W_feat/W_dir @ xf per point (fp16 storage) ----------------
__global__ __launch_bounds__(256, 2) void project_kernel(const float* __restrict__ xf,
                                                         const float* __restrict__ Wf,
                                                         const float* __restrict__ Wd,
                                                         h4* __restrict__ P0h,
                                                         h4* __restrict__ D0h){
  __shared__ float A[D_ * 64];
  const int b  = blockIdx.y;
  const int m0 = blockIdx.x * 64;
  const int t  = threadIdx.x;
  const int c  = t & 63;
  const int mg = t >> 6;
  const size_t xb = (size_t)b * D_ * N_;

  float wf[64], wd[64];
  #pragma unroll
  for (int q = 0; q < 32; ++q){
    float2 uf = *(const float2*)(Wf + c*64 + q*2);
    wf[q*2] = uf.x; wf[q*2+1] = uf.y;
    float2 ud = *(const float2*)(Wd + c*64 + q*2);
    wd[q*2] = ud.x; wd[q*2+1] = ud.y;
  }
  #pragma unroll
  for (int q = 0; q < 24; ++q){
    int p = t + 256*q;
    int d = p >> 5, i2 = (p & 31) * 2;
    float2 v = *(const float2*)(xf + xb + (size_t)d*N_ + m0 + i2);
    A[d*64 + i2] = v.x; A[d*64 + i2 + 1] = v.y;
  }
  __syncthreads();

  for (int mi = 0; mi < 16; ++mi){
    int m = mg*16 + mi;
    float p0=0,p1=0,p2=0,q0=0,q1=0,q2=0;
    #pragma unroll
    for (int ci = 0; ci < 64; ++ci){
      float f0 = A[(ci*3+0)*64 + m];
      float f1 = A[(ci*3+1)*64 + m];
      float f2 = A[(ci*3+2)*64 + m];
      p0 = fmaf(wf[ci], f0, p0); p1 = fmaf(wf[ci], f1, p1); p2 = fmaf(wf[ci], f2, p2);
      q0 = fmaf(wd[ci], f0, q0); q1 = fmaf(wd[ci], f1, q1); q2 = fmaf(wd[ci], f2, q2);
    }
    float nrm = sqrtf(p0*p0 + p1*p1 + p2*p2);
    float dsq = q0*q0 + q1*q1 + q2*q2;
    size_t base = ((size_t)b*N_ + m0 + m)*64 + c;
    h4 vp; vp.x = (f16)p0; vp.y = (f16)p1; vp.z = (f16)p2; vp.w = (f16)nrm;
    h4 vd; vd.x = (f16)q0; vd.y = (f16)q1; vd.z = (f16)q2; vd.w = (f16)dsq;
    P0h[base] = vp;
    D0h[base] = vd;
  }
}

// ---------------- K3a: neighbor occurrence counts ----------------
__global__ __launch_bounds__(256) void count_kernel(const int* __restrict__ idxin, int* __restrict__ cnt){
  int i = blockIdx.x*256 + threadIdx.x;
  if (i < B_*N_*KNb){
    int b = i / (N_*KNb);
    atomicAdd(&cnt[b*N_ + (idxin[i] & 2047)], 1);
  }
}

// ---------------- K3b: per-channel weighted sum / sumsq of norms ----------------
__global__ __launch_bounds__(256) void stats_kernel(const h4* __restrict__ P0h,
                                                    const int* __restrict__ cnt,
                                                    float* __restrict__ gs){
  const int b = blockIdx.x >> 3;
  const int chunk = blockIdx.x & 7;
  const int w = threadIdx.x >> 6, c = threadIdx.x & 63;
  float s = 0.f, s2 = 0.f;
  const int mbase = chunk*256 + w*64;
  for (int i = 0; i < 64; ++i){
    int m = mbase + i;
    float wt = (float)cnt[b*N_ + m];
    float nv = (float)P0h[((size_t)b*N_ + m)*64 + c].w;
    s  = fmaf(wt, nv, s);
    s2 = fmaf(wt*nv, nv, s2);
  }
  __shared__ float red[8][64];
  red[w][c] = s; red[4+w][c] = s2;
  __syncthreads();
  if (w == 0) atomicAdd(&gs[c],    red[0][c]+red[1][c]+red[2][c]+red[3][c]);
  if (w == 1) atomicAdd(&gs[64+c], red[4][c]+red[5][c]+red[6][c]+red[7][c]);
}

// ---------------- K4: gather + BN + nonlinearity + mean over K ----------------
__global__ __launch_bounds__(256) void out_kernel(const h4* __restrict__ P0h, const h4* __restrict__ D0h,
                                                  const int* __restrict__ idxin, const float* __restrict__ gs,
                                                  const float* __restrict__ gamma, const float* __restrict__ beta,
                                                  float* __restrict__ outp){
  const int b  = blockIdx.y;
  const int n0 = blockIdx.x * 32;
  const int w = threadIdx.x >> 6, c = threadIdx.x & 63;
  const float Ninv = 1.f / (float)(B_*N_*KNb);
  float mean = gs[c] * Ninv;
  float var  = gs[64+c] * Ninv - mean*mean;
  float istd = rsqrtf(var + 1e-5f);
  float sa = istd * gamma[c];
  float be = beta[c];
  for (int i = 0; i < 8; ++i){
    int n = n0 + w*8 + i;
    const int* ip = idxin + ((size_t)b*N_ + n)*KNb;
    float a0=0, a1=0, a2=0;
    #pragma unroll
    for (int k = 0; k < KNb; ++k){
      int m = ip[k] & 2047;
      size_t base = ((size_t)b*N_ + m)*64 + c;
      h4 P  = P0h[base];
      h4 Dv = D0h[base];
      float pw = (float)P.w;
      float nb = (pw - mean)*sa + be;
      float sc = nb / pw;
      float p0 = (float)P.x*sc, p1 = (float)P.y*sc, p2 = (float)P.z*sc;
      float d0 = (float)Dv.x, d1 = (float)Dv.y, d2 = (float)Dv.z;
      float dot = p0*d0 + p1*d1 + p2*d2;
      float f = (dot >= 0.f) ? 0.f : dot / ((float)Dv.w + 1e-6f);
      a0 += p0 - f*d0; a1 += p1 - f*d1; a2 += p2 - f*d2;
    }
    const float kinv = 1.f/11.f;
    size_t ob = (((size_t)b*64 + c)*3)*N_ + n;
    outp[ob]        = a0*kinv;
    outp[ob + N_]   = a1*kinv;
    outp[ob + 2*N_] = a2*kinv;
  }
}

extern "C" void kernel_launch(void* const* d_in, const int* in_sizes, int n_in,
                              void* d_out, int out_size, void* d_ws, size_t ws_size,
                              hipStream_t stream){
  const float* x     = (const float*)d_in[0];
  const float* Wf    = (const float*)d_in[1];
  const float* Wd    = (const float*)d_in[2];
  const float* gamma = (const float*)d_in[3];
  const float* beta  = (const float*)d_in[4];
  float* outp = (float*)d_out;

  // Workspace: 17,564,160 B total (<= 17,629,696 proven safe in R1).
  // Xs/xxd/cand alias P0h/D0h regions; all consumed before project_kernel
  // writes P0h/D0h (launch order: split -> knn -> refine -> project).
  char* ws = (char*)d_ws;
  int*    idx  = (int*)   (ws);                  // [0, 720,896)
  h4*     P0h  = (h4*)    (ws + 720896);         // [720,896, 9,109,504)
  h4*     D0h  = (h4*)    (ws + 9109504);        // [9,109,504, 17,498,112)
  short*  Xs   = (short*) (ws + 720896);         //   alias: 12,582,912 B -> ends 13,303,808
  double* xxd  = (double*)(ws + 13303808);       //   alias: 131,072 B   -> ends 13,434,880
  u16*    cand = (u16*)   (ws + 13434880);       //   alias: 524,288 B   -> ends 13,959,168
  int*    cnt  = (int*)   (ws + 17498112);       // 65,536 B
  float*  gs   = (float*) (ws + 17563648);       // 512 B

  hipMemsetAsync(cnt, 0, 65536 + 512, stream);   // zero cnt + gs
  split_kernel  <<<dim3(32, 8),  256, 0, stream>>>(x, Xs, xxd);
  knn_kernel    <<<dim3(32, 8),  256, 0, stream>>>(Xs, xxd, cand);
  refine_kernel <<<4096,         256, 0, stream>>>(x, cand, xxd, idx);
  project_kernel<<<dim3(32, 8),  256, 0, stream>>>(x, Wf, Wd, P0h, D0h);
  count_kernel  <<<704,          256, 0, stream>>>(idx, cnt);
  stats_kernel  <<<64,           256, 0, stream>>>(P0h, cnt, gs);
  out_kernel    <<<dim3(64, 8),  256, 0, stream>>>(P0h, D0h, idx, gs, gamma, beta, outp);
}

// Round 6
// 640.942 us; speedup vs baseline: 1.5412x; 1.3658x over previous
//
#include <hip/hip_runtime.h>
#include <stdint.h>

#define B_   8
#define D_   192      // Cin*3
#define N_   2048
#define KNb  11       // k+1

using u32 = uint32_t;
using u16 = unsigned short;
typedef _Float16 f16;
struct alignas(8) h4 { f16 x, y, z, w; };

typedef __attribute__((ext_vector_type(8)))  short short8;
typedef __attribute__((ext_vector_type(16))) float f32x16;

__device__ __forceinline__ float bf2f(u16 h){ union{u32 i; float f;} x; x.i = ((u32)h) << 16; return x.f; }
__device__ __forceinline__ u16 f2bf(float f){
  union{float f; u32 i;} x; x.f = f;
  u32 r = (x.i + 0x7fffu + ((x.i >> 16) & 1u)) >> 16;
  return (u16)r;
}

// ---------------- K0: bf16 hi/lo split + optional fp32 transpose + f64 xx ----------------
// Xs[b][m][k]: k<192 = hi(x[b][k][m]), k>=192 = lo (bf16).  xT[b][m][d] fp32 (if non-null).
__global__ __launch_bounds__(256) void split_kernel(const float* __restrict__ x,
                                                    short* __restrict__ Xs,
                                                    float* __restrict__ xT,
                                                    double* __restrict__ xxd){
  __shared__ float A[D_ * 64];                       // 48 KB, [d][m]
  const int b = blockIdx.y, m0 = blockIdx.x * 64, t = threadIdx.x;
  const size_t xb = (size_t)b * D_ * N_;
  #pragma unroll
  for (int q = 0; q < 48; ++q){
    int p = t + 256*q;
    int d = p >> 6, i = p & 63;
    A[d*64 + i] = x[xb + (size_t)d*N_ + m0 + i];
  }
  __syncthreads();
  const int m = t & 63, seg = t >> 6;                // 4 segs of 48 d's per point
  short* orow = Xs + ((size_t)b*N_ + m0 + m) * 384;
  #pragma unroll
  for (int c8 = 0; c8 < 6; ++c8){
    union { u16 s[8]; int4 v; } uh, ul;
    #pragma unroll
    for (int j = 0; j < 8; ++j){
      int d = seg*48 + c8*8 + j;
      float v = A[d*64 + m];
      u16 h = f2bf(v);
      uh.s[j] = h;
      ul.s[j] = f2bf(v - bf2f(h));
    }
    *(int4*)(orow + seg*48 + c8*8)       = uh.v;
    *(int4*)(orow + 192 + seg*48 + c8*8) = ul.v;
  }
  if (xT){
    float* trow = xT + ((size_t)b*N_ + m0 + m) * 192 + seg*48;
    #pragma unroll
    for (int j = 0; j < 12; ++j){
      float4 v = { A[(seg*48 + 4*j + 0)*64 + m], A[(seg*48 + 4*j + 1)*64 + m],
                   A[(seg*48 + 4*j + 2)*64 + m], A[(seg*48 + 4*j + 3)*64 + m] };
      *(float4*)(trow + 4*j) = v;
    }
  }
  if (t < 64){
    double s = 0.0;
    #pragma unroll 4
    for (int d = 0; d < D_; ++d){ double v = (double)A[d*64 + t]; s = fma(v, v, s); }
    xxd[b*N_ + m0 + t] = s;
  }
}

// ---------------- K1: MFMA kNN, 32-row stripes, 16 waves/CU ----------------
// grid (8 b, 64 stripes): linear%8 = b  ->  per-XCD L2 holds exactly one b-slice (1.5 MB).
// LDS 58,624 B -> 2 blocks/CU.  A frag-contiguous [ks][lane][16B]; B dbuf XOR-swizzled.
#define KLA   0         // 24,576 : A frags
#define KLB0  24576     // 16,384
#define KLB1  40960     // 16,384
#define KLCT  24576     // float[32*257] = 32,896 (alias B0/B1)
#define KLXXS 57472     // 256 f32
#define KLXXN 58496     // 32 f32
#define KLSZ  58624
__global__ __launch_bounds__(512, 4) void knn_kernel(const short* __restrict__ Xs,
                                                     const double* __restrict__ xxd,
                                                     u16* __restrict__ cand){
  __shared__ __align__(16) char smem[KLSZ];
  float* CT  = (float*)(smem + KLCT);
  float* XXS = (float*)(smem + KLXXS);
  float* XXN = (float*)(smem + KLXXN);

  const int b = blockIdx.x, n0 = blockIdx.y * 32;
  const int t = threadIdx.x, lane = t & 63, w = t >> 6;
  const int l31 = lane & 31, lh = lane >> 5;
  const short* xsb = Xs + (size_t)b * N_ * 384;

  // stage A-frags: [ks 0..23][lane(half,m31)][16B]
  #pragma unroll
  for (int j = 0; j < 3; ++j){
    int p = t + 512*j;                 // 0..1535
    int ks = p >> 6, ln = p & 63;
    int am = ln & 31, half = ln >> 5;
    int4 v = *(const int4*)(xsb + (size_t)(n0 + am)*384 + ks*16 + half*8);
    *(int4*)(smem + KLA + ks*1024 + ln*16) = v;
  }
  if (t < 32) XXN[t] = (float)xxd[b*N_ + n0 + t];

  float bv[10]; int bi[10];
  #pragma unroll
  for (int j = 0; j < 10; ++j){ bv[j] = -3.4e38f; bi[j] = 0; }

  for (int st = 0; st < 8; ++st){
    const int m0 = st * 256;
    if (t < 256) XXS[t] = (float)xxd[b*N_ + m0 + t];
    // stage kc=0 -> B0 (coalesced source order, swizzled dest)
    #pragma unroll
    for (int j = 0; j < 2; ++j){
      int p = t + 512*j;               // 0..1023
      int mr = p >> 2, ch = p & 3;
      int4 v = *(const int4*)(xsb + (size_t)(m0 + mr)*384 + ch*8);
      int idx = (mr>>5)*128 + (ch>>1)*64 + (ch&1)*32 + (mr&31);
      idx ^= ((idx >> 5) & 3) << 3;    // bank swizzle
      *(int4*)(smem + KLB0 + idx*16) = v;
    }
    __syncthreads();

    f32x16 acc = (f32x16)0.0f;
    for (int kc = 0; kc < 12; ++kc){
      const char* cur = smem + ((kc & 1) ? KLB1 : KLB0);
      int4 p0, p1;
      if (kc < 11){
        int mrA = t >> 2,        chA = t & 3;
        int mrB = (t + 512) >> 2, chB = t & 3;
        p0 = *(const int4*)(xsb + (size_t)(m0 + mrA)*384 + (kc+1)*32 + chA*8);
        p1 = *(const int4*)(xsb + (size_t)(m0 + mrB)*384 + (kc+1)*32 + chB*8);
      }
      #pragma unroll
      for (int ks = 0; ks < 2; ++ks){
        short8 af = *(const short8*)(smem + KLA + (kc*2 + ks)*1024 + lane*16);
        int bidx = w*128 + ks*64 + lh*32 + (l31 ^ (((ks*2 + lh) & 3) << 3));
        short8 bf = *(const short8*)(cur + bidx*16);
        acc = __builtin_amdgcn_mfma_f32_32x32x16_bf16(af, bf, acc, 0, 0, 0);
      }
      if (kc < 11){
        char* nb = smem + (((kc+1) & 1) ? KLB1 : KLB0);
        int mrA = t >> 2, mrB = (t + 512) >> 2, ch = t & 3;
        int iA = (mrA>>5)*128 + (ch>>1)*64 + (ch&1)*32 + (mrA&31);
        int iB = (mrB>>5)*128 + (ch>>1)*64 + (ch&1)*32 + (mrB&31);
        iA ^= ((iA >> 5) & 3) << 3;
        iB ^= ((iB >> 5) & 3) << 3;
        *(int4*)(nb + iA*16) = p0;
        *(int4*)(nb + iB*16) = p1;
      }
      __syncthreads();
    }

    // scatter acc -> CT[n][m], stride 257 (conflict-free)
    #pragma unroll
    for (int reg = 0; reg < 16; ++reg){
      int r = (reg & 3) + 8*(reg >> 2) + 4*lh;
      CT[r*257 + w*32 + l31] = acc[reg];
    }
    __syncthreads();

    // scan: thread (r = t&31, sub = t>>5) covers 16 m-cols
    {
      const int r = t & 31, sub = t >> 5;
      const float xn = XXN[r];
      const float* ct = CT + r*257 + sub*16;
      const float* xs = XXS + sub*16;
      #pragma unroll
      for (int i = 0; i < 16; ++i){
        float v = 2.f*ct[i] - xs[i] - xn;
        int m = m0 + sub*16 + i;
        if (v > bv[0]){
          bv[0] = v; bi[0] = m;
          #pragma unroll
          for (int s = 0; s < 9; ++s){
            if (bv[s] > bv[s+1]){
              float tv = bv[s]; bv[s] = bv[s+1]; bv[s+1] = tv;
              int   ti = bi[s]; bi[s] = bi[s+1]; bi[s+1] = ti;
            }
          }
        }
      }
    }
    __syncthreads();
  }

  // merge 16 lists x 10 per row -> top-16 window
  float* MV = CT;                                  // 32*16*10*4 = 20,480
  u16*   MI = (u16*)(smem + KLCT + 20480);         // 10,240
  {
    const int r = t & 31, sub = t >> 5;
    #pragma unroll
    for (int j = 0; j < 10; ++j){
      MV[(r*16 + sub)*10 + j] = bv[j];
      MI[(r*16 + sub)*10 + j] = (u16)bi[j];
    }
  }
  __syncthreads();
  if (t < 32){
    int head[16];
    #pragma unroll
    for (int q = 0; q < 16; ++q) head[q] = 9;
    const size_t ob = ((size_t)b*N_ + n0 + t) * 16;
    for (int s = 0; s < 16; ++s){
      float bvv = -3.4e38f; int bm = 0x7fffffff, bq = 0;
      #pragma unroll
      for (int q = 0; q < 16; ++q){
        int hh = head[q];
        if (hh >= 0){
          float v = MV[(t*16 + q)*10 + hh];
          int   m = (int)MI[(t*16 + q)*10 + hh];
          if ((v > bvv) || ((v == bvv) && (m < bm))){ bvv = v; bm = m; bq = q; }
        }
      }
      cand[ob + s] = (u16)(bm & 2047);
      head[bq]--;
    }
  }
}

// ---------------- K1b-fast: f64 refine from coalesced xT ----------------
__global__ __launch_bounds__(256) void refine_fast(const float* __restrict__ xT,
                                                   const u16* __restrict__ cand,
                                                   const double* __restrict__ xxd,
                                                   int* __restrict__ idxout){
  __shared__ double dls[4][16];
  __shared__ int    mls[4][16];
  const int wv = threadIdx.x >> 6, ln = threadIdx.x & 63;
  const int g = blockIdx.x * 4 + wv;
  const int b = g >> 11, n = g & 2047;
  const int c = ln >> 2, part = ln & 3;
  const int m = (int)cand[(size_t)g*16 + c] & 2047;
  const float* pn = xT + ((size_t)b*N_ + n)*192 + part*48;
  const float* pm = xT + ((size_t)b*N_ + m)*192 + part*48;
  double s = 0.0;
  #pragma unroll 8
  for (int d = 0; d < 48; ++d)
    s = fma((double)pn[d], (double)pm[d], s);
  s += __shfl_down(s, 2, 64);
  s += __shfl_down(s, 1, 64);
  if (part == 0){
    dls[wv][c] = 2.0*s - xxd[b*N_ + n] - xxd[b*N_ + m];
    mls[wv][c] = m;
  }
  __syncthreads();
  if (ln == 0){
    double vv[16]; int mm[16];
    #pragma unroll
    for (int i = 0; i < 16; ++i){ vv[i] = dls[wv][i]; mm[i] = mls[wv][i]; }
    for (int s2 = 0; s2 < KNb; ++s2){
      int best = 0;
      #pragma unroll
      for (int i = 1; i < 16; ++i){
        bool better = (vv[i] > vv[best]) || ((vv[i] == vv[best]) && (mm[i] < mm[best]));
        if (better) best = i;
      }
      idxout[(size_t)g*KNb + s2] = mm[best];
      vv[best] = -1.0e308;
    }
  }
}

// ---------------- K1b-slow: f64 refine from original layout (ws fallback) ----------------
__global__ __launch_bounds__(256) void refine_slow(const float* __restrict__ xf,
                                                   const u16* __restrict__ cand,
                                                   const double* __restrict__ xxd,
                                                   int* __restrict__ idxout){
  __shared__ double dls[4][16];
  __shared__ int    mls[4][16];
  const int wv = threadIdx.x >> 6, ln = threadIdx.x & 63;
  const int g = blockIdx.x * 4 + wv;
  const int b = g >> 11, n = g & 2047;
  const int c = ln >> 2, part = ln & 3;
  const int m = (int)cand[(size_t)g*16 + c] & 2047;
  const float* xb = xf + (size_t)b * D_ * N_;
  const float* pn = xb + (size_t)(part*48) * N_ + n;
  const float* pm = xb + (size_t)(part*48) * N_ + m;
  double s = 0.0;
  #pragma unroll 8
  for (int d = 0; d < 48; ++d)
    s = fma((double)pn[(size_t)d*N_], (double)pm[(size_t)d*N_], s);
  s += __shfl_down(s, 2, 64);
  s += __shfl_down(s, 1, 64);
  if (part == 0){
    dls[wv][c] = 2.0*s - xxd[b*N_ + n] - xxd[b*N_ + m];
    mls[wv][c] = m;
  }
  __syncthreads();
  if (ln == 0){
    double vv[16]; int mm[16];
    #pragma unroll
    for (int i = 0; i < 16; ++i){ vv[i] = dls[wv][i]; mm[i] = mls[wv][i]; }
    for (int s2 = 0; s2 < KNb; ++s2){
      int best = 0;
      #pragma unroll
      for (int i = 1; i < 16; ++i){
        bool better = (vv[i] > vv[best]) || ((vv[i] == vv[best]) && (mm[i] < mm[best]));
        if (better) best = i;
      }
      idxout[(size_t)g*KNb + s2] = mm[best];
      vv[best] = -1.0e308;
    }
  }
}

// ---------------- K2: P0/D0 = W_feat/W_dir @ xf per point (fp16 storage) ----------------
__global__ __launch_bounds__(256, 2) void project_kernel(const float* __restrict__ xf,
                                                         const float* __restrict__ Wf,
                                                         const float* __restrict__ Wd,
                                                         h4* __restrict__ P0h,
                                                         h4* __restrict__ D0h){
  __shared__ float A[D_ * 64];
  const int b  = blockIdx.y;
  const int m0 = blockIdx.x * 64;
  const int t  = threadIdx.x;
  const int c  = t & 63;
  const int mg = t >> 6;
  const size_t xb = (size_t)b * D_ * N_;

  float wf[64], wd[64];
  #pragma unroll
  for (int q = 0; q < 32; ++q){
    float2 uf = *(const float2*)(Wf + c*64 + q*2);
    wf[q*2] = uf.x; wf[q*2+1] = uf.y;
    float2 ud = *(const float2*)(Wd + c*64 + q*2);
    wd[q*2] = ud.x; wd[q*2+1] = ud.y;
  }
  #pragma unroll
  for (int q = 0; q < 24; ++q){
    int p = t + 256*q;
    int d = p >> 5, i2 = (p & 31) * 2;
    float2 v = *(const float2*)(xf + xb + (size_t)d*N_ + m0 + i2);
    A[d*64 + i2] = v.x; A[d*64 + i2 + 1] = v.y;
  }
  __syncthreads();

  for (int mi = 0; mi < 16; ++mi){
    int m = mg*16 + mi;
    float p0=0,p1=0,p2=0,q0=0,q1=0,q2=0;
    #pragma unroll
    for (int ci = 0; ci < 64; ++ci){
      float f0 = A[(ci*3+0)*64 + m];
      float f1 = A[(ci*3+1)*64 + m];
      float f2 = A[(ci*3+2)*64 + m];
      p0 = fmaf(wf[ci], f0, p0); p1 = fmaf(wf[ci], f1, p1); p2 = fmaf(wf[ci], f2, p2);
      q0 = fmaf(wd[ci], f0, q0); q1 = fmaf(wd[ci], f1, q1); q2 = fmaf(wd[ci], f2, q2);
    }
    float nrm = sqrtf(p0*p0 + p1*p1 + p2*p2);
    float dsq = q0*q0 + q1*q1 + q2*q2;
    size_t base = ((size_t)b*N_ + m0 + m)*64 + c;
    h4 vp; vp.x = (f16)p0; vp.y = (f16)p1; vp.z = (f16)p2; vp.w = (f16)nrm;
    h4 vd; vd.x = (f16)q0; vd.y = (f16)q1; vd.z = (f16)q2; vd.w = (f16)dsq;
    P0h[base] = vp;
    D0h[base] = vd;
  }
}

// ---------------- K3a: neighbor occurrence counts ----------------
__global__ __launch_bounds__(256) void count_kernel(const int* __restrict__ idxin, int* __restrict__ cnt){
  int i = blockIdx.x*256 + threadIdx.x;
  if (i < B_*N_*KNb){
    int b = i / (N_*KNb);
    atomicAdd(&cnt[b*N_ + (idxin[i] & 2047)], 1);
  }
}

// ---------------- K3b: per-channel weighted sum / sumsq of norms ----------------
__global__ __launch_bounds__(256) void stats_kernel(const h4* __restrict__ P0h,
                                                    const int* __restrict__ cnt,
                                                    float* __restrict__ gs){
  const int b = blockIdx.x >> 3;
  const int chunk = blockIdx.x & 7;
  const int w = threadIdx.x >> 6, c = threadIdx.x & 63;
  float s = 0.f, s2 = 0.f;
  const int mbase = chunk*256 + w*64;
  for (int i = 0; i < 64; ++i){
    int m = mbase + i;
    float wt = (float)cnt[b*N_ + m];
    float nv = (float)P0h[((size_t)b*N_ + m)*64 + c].w;
    s  = fmaf(wt, nv, s);
    s2 = fmaf(wt*nv, nv, s2);
  }
  __shared__ float red[8][64];
  red[w][c] = s; red[4+w][c] = s2;
  __syncthreads();
  if (w == 0) atomicAdd(&gs[c],    red[0][c]+red[1][c]+red[2][c]+red[3][c]);
  if (w == 1) atomicAdd(&gs[64+c], red[4][c]+red[5][c]+red[6][c]+red[7][c]);
}

// ---------------- K4: gather + BN + nonlinearity + mean over K (LDS-transposed stores) ----------------
__global__ __launch_bounds__(512) void out_kernel(const h4* __restrict__ P0h, const h4* __restrict__ D0h,
                                                  const int* __restrict__ idxin, const float* __restrict__ gs,
                                                  const float* __restrict__ gamma, const float* __restrict__ beta,
                                                  float* __restrict__ outp){
  __shared__ float res[64 * 193];                  // 49,408 B -> 3 blocks/CU
  const int b  = blockIdx.y;
  const int n0 = blockIdx.x * 64;
  const int t = threadIdx.x, w = t >> 6, c = t & 63;
  const float Ninv = 1.f / (float)(B_*N_*KNb);
  float mean = gs[c] * Ninv;
  float var  = gs[64+c] * Ninv - mean*mean;
  float istd = rsqrtf(var + 1e-5f);
  float sa = istd * gamma[c];
  float be = beta[c];
  const float kinv = 1.f/11.f;
  for (int i = 0; i < 8; ++i){
    int n = n0 + w*8 + i;
    const int* ip = idxin + ((size_t)b*N_ + n)*KNb;
    float a0=0, a1=0, a2=0;
    #pragma unroll
    for (int k = 0; k < KNb; ++k){
      int m = ip[k] & 2047;
      size_t base = ((size_t)b*N_ + m)*64 + c;
      h4 P  = P0h[base];
      h4 Dv = D0h[base];
      float pw = (float)P.w;
      float nb = (pw - mean)*sa + be;
      float sc = nb / pw;
      float p0 = (float)P.x*sc, p1 = (float)P.y*sc, p2 = (float)P.z*sc;
      float d0 = (float)Dv.x, d1 = (float)Dv.y, d2 = (float)Dv.z;
      float dot = p0*d0 + p1*d1 + p2*d2;
      float f = (dot >= 0.f) ? 0.f : dot / ((float)Dv.w + 1e-6f);
      a0 += p0 - f*d0; a1 += p1 - f*d1; a2 += p2 - f*d2;
    }
    int row = w*8 + i;
    res[row*193 + 3*c + 0] = a0*kinv;
    res[row*193 + 3*c + 1] = a1*kinv;
    res[row*193 + 3*c + 2] = a2*kinv;
  }
  __syncthreads();
  #pragma unroll
  for (int j = 0; j < 6; ++j){
    int p = t + 512*j;                 // 0..3071
    int cdim = p >> 4, nq = p & 15;    // cdim = c*3+dim
    float4 v = { res[(nq*4 + 0)*193 + cdim], res[(nq*4 + 1)*193 + cdim],
                 res[(nq*4 + 2)*193 + cdim], res[(nq*4 + 3)*193 + cdim] };
    *(float4*)(outp + ((size_t)b*192 + cdim)*N_ + n0 + nq*4) = v;
  }
}

extern "C" void kernel_launch(void* const* d_in, const int* in_sizes, int n_in,
                              void* d_out, int out_size, void* d_ws, size_t ws_size,
                              hipStream_t stream){
  const float* x     = (const float*)d_in[0];
  const float* Wf    = (const float*)d_in[1];
  const float* Wd    = (const float*)d_in[2];
  const float* gamma = (const float*)d_in[3];
  const float* beta  = (const float*)d_in[4];
  float* outp = (float*)d_out;

  char* ws = (char*)d_ws;
  const bool big = ws_size >= 30408704ull;   // constant per process -> graph-capture safe

  int *idx, *cnt; float *gs, *xT; short *Xs; double *xxd; u16 *cand; h4 *P0h, *D0h;
  if (big){
    idx  = (int*)   (ws);                 // 720,896
    cnt  = (int*)   (ws + 720896);        // 65,536
    gs   = (float*) (ws + 786432);        // 512
    P0h  = (h4*)    (ws + 1048576);       // 8,388,608
    D0h  = (h4*)    (ws + 9437184);       // 8,388,608 (ends 17,825,792)
    Xs   = (short*) (ws + 1048576);       //   alias, consumed pre-project
    xxd  = (double*)(ws + 13631488);      //   alias
    cand = (u16*)   (ws + 13762560);      //   alias
    xT   = (float*) (ws + 17825792);      // 12,582,912 (ends 30,408,704)
  } else {
    idx  = (int*)   (ws);
    P0h  = (h4*)    (ws + 720896);
    D0h  = (h4*)    (ws + 9109504);
    Xs   = (short*) (ws + 720896);
    xxd  = (double*)(ws + 13303808);
    cand = (u16*)   (ws + 13434880);
    cnt  = (int*)   (ws + 17498112);
    gs   = (float*) (ws + 17563648);
    xT   = nullptr;
  }

  hipMemsetAsync(cnt, 0, 66048, stream);   // zero cnt + gs (contiguous)
  split_kernel  <<<dim3(32, 8),  256, 0, stream>>>(x, Xs, xT, xxd);
  knn_kernel    <<<dim3(8, 64),  512, 0, stream>>>(Xs, xxd, cand);
  if (big) refine_fast<<<4096,   256, 0, stream>>>(xT, cand, xxd, idx);
  else     refine_slow<<<4096,   256, 0, stream>>>(x, cand, xxd, idx);
  project_kernel<<<dim3(32, 8),  256, 0, stream>>>(x, Wf, Wd, P0h, D0h);
  count_kernel  <<<704,          256, 0, stream>>>(idx, cnt);
  stats_kernel  <<<64,           256, 0, stream>>>(P0h, cnt, gs);
  out_kernel    <<<dim3(32, 8),  512, 0, stream>>>(P0h, D0h, idx, gs, gamma, beta, outp);
}

// Round 7
// 384.414 us; speedup vs baseline: 2.5697x; 1.6673x over previous
//
#include <hip/hip_runtime.h>
#include <stdint.h>

#define B_   8
#define D_   192      // Cin*3
#define N_   2048
#define KNb  11       // k+1

using u32 = uint32_t;
using u16 = unsigned short;
typedef _Float16 f16;
struct alignas(8) h4 { f16 x, y, z, w; };

typedef __attribute__((ext_vector_type(8)))  short short8;
typedef __attribute__((ext_vector_type(16))) float f32x16;

__device__ __forceinline__ float bf2f(u16 h){ union{u32 i; float f;} x; x.i = ((u32)h) << 16; return x.f; }
__device__ __forceinline__ u16 f2bf(float f){
  union{float f; u32 i;} x; x.f = f;
  u32 r = (x.i + 0x7fffu + ((x.i >> 16) & 1u)) >> 16;
  return (u16)r;
}

// ---------------- K0: bf16 hi/lo split + fp32 transpose + f64 xx ----------------
__global__ __launch_bounds__(256) void split_kernel(const float* __restrict__ x,
                                                    short* __restrict__ Xs,
                                                    float* __restrict__ xT,
                                                    double* __restrict__ xxd){
  __shared__ float A[D_ * 64];                       // 48 KB, [d][m]
  const int b = blockIdx.y, m0 = blockIdx.x * 64, t = threadIdx.x;
  const size_t xb = (size_t)b * D_ * N_;
  #pragma unroll
  for (int q = 0; q < 48; ++q){
    int p = t + 256*q;
    int d = p >> 6, i = p & 63;
    A[d*64 + i] = x[xb + (size_t)d*N_ + m0 + i];
  }
  __syncthreads();
  const int m = t & 63, seg = t >> 6;                // 4 segs of 48 d's per point
  short* orow = Xs + ((size_t)b*N_ + m0 + m) * 384;
  #pragma unroll
  for (int c8 = 0; c8 < 6; ++c8){
    union { u16 s[8]; int4 v; } uh, ul;
    #pragma unroll
    for (int j = 0; j < 8; ++j){
      int d = seg*48 + c8*8 + j;
      float v = A[d*64 + m];
      u16 h = f2bf(v);
      uh.s[j] = h;
      ul.s[j] = f2bf(v - bf2f(h));
    }
    *(int4*)(orow + seg*48 + c8*8)       = uh.v;
    *(int4*)(orow + 192 + seg*48 + c8*8) = ul.v;
  }
  {
    float* trow = xT + ((size_t)b*N_ + m0 + m) * 192 + seg*48;
    #pragma unroll
    for (int j = 0; j < 12; ++j){
      float4 v = { A[(seg*48 + 4*j + 0)*64 + m], A[(seg*48 + 4*j + 1)*64 + m],
                   A[(seg*48 + 4*j + 2)*64 + m], A[(seg*48 + 4*j + 3)*64 + m] };
      *(float4*)(trow + 4*j) = v;
    }
  }
  if (t < 64){
    double s = 0.0;
    #pragma unroll 4
    for (int d = 0; d < D_; ++d){ double v = (double)A[d*64 + t]; s = fma(v, v, s); }
    xxd[b*N_ + m0 + t] = s;
  }
}

// ---------------- K1: MFMA kNN, 32-row stripes, 16 waves/CU ----------------
// grid (8 b, 64 stripes): linear%8 = b -> per-XCD L2 holds one b-slice (1.5 MB).
#define KLA   0         // 24,576 : A frags
#define KLB0  24576     // 16,384
#define KLB1  40960     // 16,384
#define KLCT  24576     // float[32*257] = 32,896 (alias B0/B1)
#define KLXXS 57472     // 256 f32
#define KLXXN 58496     // 32 f32
#define KLSZ  58624
__global__ __launch_bounds__(512, 4) void knn_kernel(const short* __restrict__ Xs,
                                                     const double* __restrict__ xxd,
                                                     u16* __restrict__ cand){
  __shared__ __align__(16) char smem[KLSZ];
  float* CT  = (float*)(smem + KLCT);
  float* XXS = (float*)(smem + KLXXS);
  float* XXN = (float*)(smem + KLXXN);

  const int b = blockIdx.x, n0 = blockIdx.y * 32;
  const int t = threadIdx.x, lane = t & 63, w = t >> 6;
  const int l31 = lane & 31, lh = lane >> 5;
  const short* xsb = Xs + (size_t)b * N_ * 384;

  #pragma unroll
  for (int j = 0; j < 3; ++j){
    int p = t + 512*j;                 // 0..1535
    int ks = p >> 6, ln = p & 63;
    int am = ln & 31, half = ln >> 5;
    int4 v = *(const int4*)(xsb + (size_t)(n0 + am)*384 + ks*16 + half*8);
    *(int4*)(smem + KLA + ks*1024 + ln*16) = v;
  }
  if (t < 32) XXN[t] = (float)xxd[b*N_ + n0 + t];

  float bv[10]; int bi[10];
  #pragma unroll
  for (int j = 0; j < 10; ++j){ bv[j] = -3.4e38f; bi[j] = 0; }

  for (int st = 0; st < 8; ++st){
    const int m0 = st * 256;
    if (t < 256) XXS[t] = (float)xxd[b*N_ + m0 + t];
    #pragma unroll
    for (int j = 0; j < 2; ++j){
      int p = t + 512*j;
      int mr = p >> 2, ch = p & 3;
      int4 v = *(const int4*)(xsb + (size_t)(m0 + mr)*384 + ch*8);
      int idx = (mr>>5)*128 + (ch>>1)*64 + (ch&1)*32 + (mr&31);
      idx ^= ((idx >> 5) & 3) << 3;
      *(int4*)(smem + KLB0 + idx*16) = v;
    }
    __syncthreads();

    f32x16 acc = (f32x16)0.0f;
    for (int kc = 0; kc < 12; ++kc){
      const char* cur = smem + ((kc & 1) ? KLB1 : KLB0);
      int4 p0, p1;
      if (kc < 11){
        int mrA = t >> 2;
        int mrB = (t + 512) >> 2;
        int ch = t & 3;
        p0 = *(const int4*)(xsb + (size_t)(m0 + mrA)*384 + (kc+1)*32 + ch*8);
        p1 = *(const int4*)(xsb + (size_t)(m0 + mrB)*384 + (kc+1)*32 + ch*8);
      }
      #pragma unroll
      for (int ks = 0; ks < 2; ++ks){
        short8 af = *(const short8*)(smem + KLA + (kc*2 + ks)*1024 + lane*16);
        int bidx = w*128 + ks*64 + lh*32 + (l31 ^ (((ks*2 + lh) & 3) << 3));
        short8 bf = *(const short8*)(cur + bidx*16);
        acc = __builtin_amdgcn_mfma_f32_32x32x16_bf16(af, bf, acc, 0, 0, 0);
      }
      if (kc < 11){
        char* nb = smem + (((kc+1) & 1) ? KLB1 : KLB0);
        int mrA = t >> 2, mrB = (t + 512) >> 2, ch = t & 3;
        int iA = (mrA>>5)*128 + (ch>>1)*64 + (ch&1)*32 + (mrA&31);
        int iB = (mrB>>5)*128 + (ch>>1)*64 + (ch&1)*32 + (mrB&31);
        iA ^= ((iA >> 5) & 3) << 3;
        iB ^= ((iB >> 5) & 3) << 3;
        *(int4*)(nb + iA*16) = p0;
        *(int4*)(nb + iB*16) = p1;
      }
      __syncthreads();
    }

    #pragma unroll
    for (int reg = 0; reg < 16; ++reg){
      int r = (reg & 3) + 8*(reg >> 2) + 4*lh;
      CT[r*257 + w*32 + l31] = acc[reg];
    }
    __syncthreads();

    {
      const int r = t & 31, sub = t >> 5;
      const float xn = XXN[r];
      const float* ct = CT + r*257 + sub*16;
      const float* xs = XXS + sub*16;
      #pragma unroll
      for (int i = 0; i < 16; ++i){
        float v = 2.f*ct[i] - xs[i] - xn;
        int m = m0 + sub*16 + i;
        if (v > bv[0]){
          bv[0] = v; bi[0] = m;
          #pragma unroll
          for (int s = 0; s < 9; ++s){
            if (bv[s] > bv[s+1]){
              float tv = bv[s]; bv[s] = bv[s+1]; bv[s+1] = tv;
              int   ti = bi[s]; bi[s] = bi[s+1]; bi[s+1] = ti;
            }
          }
        }
      }
    }
    __syncthreads();
  }

  // merge 16 lists x 10 per row -> top-16 window (static indexing only)
  float* MV = CT;                                  // 32*16*10*4 = 20,480
  u16*   MI = (u16*)(smem + KLCT + 20480);         // 10,240
  {
    const int r = t & 31, sub = t >> 5;
    #pragma unroll
    for (int j = 0; j < 10; ++j){
      MV[(r*16 + sub)*10 + j] = bv[j];
      MI[(r*16 + sub)*10 + j] = (u16)bi[j];
    }
  }
  __syncthreads();
  if (t < 32){
    int head[16];
    #pragma unroll
    for (int q = 0; q < 16; ++q) head[q] = 9;
    const size_t ob = ((size_t)b*N_ + n0 + t) * 16;
    for (int s = 0; s < 16; ++s){
      float bvv = -3.4e38f; int bm = 0x7fffffff, bq = 0;
      #pragma unroll
      for (int q = 0; q < 16; ++q){
        int hh = head[q];
        if (hh >= 0){
          float v = MV[(t*16 + q)*10 + hh];
          int   m = (int)MI[(t*16 + q)*10 + hh];
          if ((v > bvv) || ((v == bvv) && (m < bm))){ bvv = v; bm = m; bq = q; }
        }
      }
      cand[ob + s] = (u16)(bm & 2047);
      #pragma unroll
      for (int q = 0; q < 16; ++q) head[q] -= (q == bq) ? 1 : 0;
    }
  }
}

// ---------------- K1b: f64 refine, register-only, shuffle-rank top-11 ----------------
// wave = one point; lane = (cand c = ln>>2, part = ln&3); float4 gathers from xT.
__global__ __launch_bounds__(256) void refine_kernel(const float* __restrict__ xT,
                                                     const u16* __restrict__ cand,
                                                     const double* __restrict__ xxd,
                                                     int* __restrict__ idxout){
  const int wv = threadIdx.x >> 6, ln = threadIdx.x & 63;
  const int g = blockIdx.x * 4 + wv;               // 0..16383
  const int b = g >> 11, n = g & 2047;
  const int c = ln >> 2, part = ln & 3;
  const int m = (int)cand[(size_t)g*16 + c] & 2047;
  const float4* pn = (const float4*)(xT + ((size_t)b*N_ + n)*192 + part*48);
  const float4* pm = (const float4*)(xT + ((size_t)b*N_ + m)*192 + part*48);
  double s = 0.0;
  #pragma unroll
  for (int j = 0; j < 12; ++j){                    // d ascending: same f64 order as before
    float4 a = pn[j], bb = pm[j];
    s = fma((double)a.x, (double)bb.x, s);
    s = fma((double)a.y, (double)bb.y, s);
    s = fma((double)a.z, (double)bb.z, s);
    s = fma((double)a.w, (double)bb.w, s);
  }
  s += __shfl_down(s, 2, 64);
  s += __shfl_down(s, 1, 64);                      // part==0 lanes hold full dot
  double v = 2.0*s - xxd[b*N_ + n] - xxd[b*N_ + m];
  int rank = 0;
  #pragma unroll
  for (int q = 0; q < 16; ++q){
    double vq = __shfl(v, q*4, 64);
    int    mq = __shfl(m, q*4, 64);
    bool beat = (vq > v) || ((vq == v) && (mq < m));
    rank += beat ? 1 : 0;
  }
  if (part == 0 && rank < KNb)
    idxout[(size_t)g*KNb + rank] = m;
}

// ---------------- K2: P0/D0 from xT (coalesced + broadcast LDS) ----------------
__global__ __launch_bounds__(256, 2) void project_kernel(const float* __restrict__ xT,
                                                         const float* __restrict__ Wf,
                                                         const float* __restrict__ Wd,
                                                         h4* __restrict__ P0h,
                                                         h4* __restrict__ D0h){
  __shared__ float A[64 * 192];                    // 48 KB, [m][e]
  const int b = blockIdx.x, m0 = blockIdx.y * 64, t = threadIdx.x;
  const int c = t & 63, mg = t >> 6;

  float wf[64], wd[64];
  #pragma unroll
  for (int q = 0; q < 16; ++q){
    float4 uf = *(const float4*)(Wf + c*64 + q*4);
    wf[q*4+0]=uf.x; wf[q*4+1]=uf.y; wf[q*4+2]=uf.z; wf[q*4+3]=uf.w;
    float4 ud = *(const float4*)(Wd + c*64 + q*4);
    wd[q*4+0]=ud.x; wd[q*4+1]=ud.y; wd[q*4+2]=ud.z; wd[q*4+3]=ud.w;
  }
  {
    const float4* src = (const float4*)(xT + ((size_t)b*N_ + m0)*192);
    float4* dst = (float4*)A;
    #pragma unroll
    for (int j = 0; j < 12; ++j) dst[t + 256*j] = src[t + 256*j];
  }
  __syncthreads();

  for (int mi = 0; mi < 16; ++mi){
    int m = mg*16 + mi;
    const float4* row = (const float4*)(A + m*192);
    float p[3] = {0.f,0.f,0.f}, qv[3] = {0.f,0.f,0.f};
    #pragma unroll
    for (int v4 = 0; v4 < 48; ++v4){
      float4 f = row[v4];
      const int e = v4*4;
      p [(e+0)%3] = fmaf(wf[(e+0)/3], f.x, p [(e+0)%3]);
      qv[(e+0)%3] = fmaf(wd[(e+0)/3], f.x, qv[(e+0)%3]);
      p [(e+1)%3] = fmaf(wf[(e+1)/3], f.y, p [(e+1)%3]);
      qv[(e+1)%3] = fmaf(wd[(e+1)/3], f.y, qv[(e+1)%3]);
      p [(e+2)%3] = fmaf(wf[(e+2)/3], f.z, p [(e+2)%3]);
      qv[(e+2)%3] = fmaf(wd[(e+2)/3], f.z, qv[(e+2)%3]);
      p [(e+3)%3] = fmaf(wf[(e+3)/3], f.w, p [(e+3)%3]);
      qv[(e+3)%3] = fmaf(wd[(e+3)/3], f.w, qv[(e+3)%3]);
    }
    float nrm = sqrtf(p[0]*p[0] + p[1]*p[1] + p[2]*p[2]);
    float dsq = qv[0]*qv[0] + qv[1]*qv[1] + qv[2]*qv[2];
    size_t base = ((size_t)b*N_ + m0 + m)*64 + c;
    h4 vp; vp.x = (f16)p[0];  vp.y = (f16)p[1];  vp.z = (f16)p[2];  vp.w = (f16)nrm;
    h4 vd; vd.x = (f16)qv[0]; vd.y = (f16)qv[1]; vd.z = (f16)qv[2]; vd.w = (f16)dsq;
    P0h[base] = vp;
    D0h[base] = vd;
  }
}

// ---------------- K3a: neighbor occurrence counts ----------------
__global__ __launch_bounds__(256) void count_kernel(const int* __restrict__ idxin, int* __restrict__ cnt){
  int i = blockIdx.x*256 + threadIdx.x;
  if (i < B_*N_*KNb){
    int b = i / (N_*KNb);
    atomicAdd(&cnt[b*N_ + (idxin[i] & 2047)], 1);
  }
}

// ---------------- K3b: per-channel weighted sum / sumsq of norms ----------------
__global__ __launch_bounds__(256) void stats_kernel(const h4* __restrict__ P0h,
                                                    const int* __restrict__ cnt,
                                                    float* __restrict__ gs){
  const int b = blockIdx.x >> 3;
  const int chunk = blockIdx.x & 7;
  const int w = threadIdx.x >> 6, c = threadIdx.x & 63;
  float s = 0.f, s2 = 0.f;
  const int mbase = chunk*256 + w*64;
  for (int i = 0; i < 64; ++i){
    int m = mbase + i;
    float wt = (float)cnt[b*N_ + m];
    float nv = (float)P0h[((size_t)b*N_ + m)*64 + c].w;
    s  = fmaf(wt, nv, s);
    s2 = fmaf(wt*nv, nv, s2);
  }
  __shared__ float red[8][64];
  red[w][c] = s; red[4+w][c] = s2;
  __syncthreads();
  if (w == 0) atomicAdd(&gs[c],    red[0][c]+red[1][c]+red[2][c]+red[3][c]);
  if (w == 1) atomicAdd(&gs[64+c], red[4][c]+red[5][c]+red[6][c]+red[7][c]);
}

// ---------------- K4: gather + BN + nonlinearity + mean over K ----------------
// grid (8 b, 32 stripes): XCD-local P0h/D0h slice (2.1 MB < 4 MB L2).
__global__ __launch_bounds__(512) void out_kernel(const h4* __restrict__ P0h, const h4* __restrict__ D0h,
                                                  const int* __restrict__ idxin, const float* __restrict__ gs,
                                                  const float* __restrict__ gamma, const float* __restrict__ beta,
                                                  float* __restrict__ outp){
  __shared__ float res[64 * 193];                  // 49,408 B
  const int b  = blockIdx.x;
  const int n0 = blockIdx.y * 64;
  const int t = threadIdx.x, w = t >> 6, c = t & 63;
  const float Ninv = 1.f / (float)(B_*N_*KNb);
  float mean = gs[c] * Ninv;
  float var  = gs[64+c] * Ninv - mean*mean;
  float istd = rsqrtf(var + 1e-5f);
  float sa = istd * gamma[c];
  float be = beta[c];
  const float kinv = 1.f/11.f;
  for (int i = 0; i < 8; ++i){
    int n = n0 + w*8 + i;
    const int* ip = idxin + ((size_t)b*N_ + n)*KNb;
    float a0=0, a1=0, a2=0;
    #pragma unroll
    for (int k = 0; k < KNb; ++k){
      int m = ip[k] & 2047;
      size_t base = ((size_t)b*N_ + m)*64 + c;
      h4 P  = P0h[base];
      h4 Dv = D0h[base];
      float pw = (float)P.w;
      float nb = (pw - mean)*sa + be;
      float sc = nb / pw;
      float p0 = (float)P.x*sc, p1 = (float)P.y*sc, p2 = (float)P.z*sc;
      float d0 = (float)Dv.x, d1 = (float)Dv.y, d2 = (float)Dv.z;
      float dot = p0*d0 + p1*d1 + p2*d2;
      float f = (dot >= 0.f) ? 0.f : dot / ((float)Dv.w + 1e-6f);
      a0 += p0 - f*d0; a1 += p1 - f*d1; a2 += p2 - f*d2;
    }
    int row = w*8 + i;
    res[row*193 + 3*c + 0] = a0*kinv;
    res[row*193 + 3*c + 1] = a1*kinv;
    res[row*193 + 3*c + 2] = a2*kinv;
  }
  __syncthreads();
  #pragma unroll
  for (int j = 0; j < 6; ++j){
    int p = t + 512*j;
    int cdim = p >> 4, nq = p & 15;
    float4 v = { res[(nq*4 + 0)*193 + cdim], res[(nq*4 + 1)*193 + cdim],
                 res[(nq*4 + 2)*193 + cdim], res[(nq*4 + 3)*193 + cdim] };
    *(float4*)(outp + ((size_t)b*192 + cdim)*N_ + n0 + nq*4) = v;
  }
}

extern "C" void kernel_launch(void* const* d_in, const int* in_sizes, int n_in,
                              void* d_out, int out_size, void* d_ws, size_t ws_size,
                              hipStream_t stream){
  const float* x     = (const float*)d_in[0];
  const float* Wf    = (const float*)d_in[1];
  const float* Wd    = (const float*)d_in[2];
  const float* gamma = (const float*)d_in[3];
  const float* beta  = (const float*)d_in[4];
  float* outp = (float*)d_out;

  // ws >= 30,408,704 B proven in R6 (refine_fast ran).
  char* ws = (char*)d_ws;
  int*    idx  = (int*)   (ws);                 // 720,896
  int*    cnt  = (int*)   (ws + 720896);        // 65,536
  float*  gs   = (float*) (ws + 786432);        // 512
  h4*     P0h  = (h4*)    (ws + 1048576);       // 8,388,608
  h4*     D0h  = (h4*)    (ws + 9437184);       // 8,388,608 (ends 17,825,792)
  short*  Xs   = (short*) (ws + 1048576);       //   alias, consumed pre-project
  double* xxd  = (double*)(ws + 13631488);      //   alias (lives in D0h region pre-project)
  u16*    cand = (u16*)   (ws + 13762560);      //   alias
  float*  xT   = (float*) (ws + 17825792);      // 12,582,912 (ends 30,408,704)

  hipMemsetAsync(cnt, 0, 66048, stream);        // zero cnt + gs (contiguous)
  split_kernel  <<<dim3(32, 8),  256, 0, stream>>>(x, Xs, xT, xxd);
  knn_kernel    <<<dim3(8, 64),  512, 0, stream>>>(Xs, xxd, cand);
  refine_kernel <<<4096,         256, 0, stream>>>(xT, cand, xxd, idx);
  project_kernel<<<dim3(8, 32),  256, 0, stream>>>(xT, Wf, Wd, P0h, D0h);
  count_kernel  <<<704,          256, 0, stream>>>(idx, cnt);
  stats_kernel  <<<64,           256, 0, stream>>>(P0h, cnt, gs);
  out_kernel    <<<dim3(8, 32),  512, 0, stream>>>(P0h, D0h, idx, gs, gamma, beta, outp);
}